// Round 3
// baseline (674.120 us; speedup 1.0000x reference)
//
#include <hip/hip_runtime.h>
#include <hip/hip_bf16.h>
#include <math.h>
#include <stdint.h>

// SimpleSSMLayer on gfx950 — Round 12: CHUNK-PARALLEL SCAN.
// R11 counters: kscan = 418/664 us, Occupancy 22.7% (2 blocks/CU), VALUBusy
// 46%, 2048 serial steps/block — latency-bound, ~85% stall. The linear
// recurrence h=e*h+f is associative: split T into P=16 chunks of 128.
//   kscanA (8192 blk): local scan from 0, emit decay-product A_c + h_end.
//   kscanH (512 blk) : 16-step sequential combine -> per-chunk H_init.
//   kscanB (8192 blk): recompute dt/u (cheap), scan from H_init, y + gate.
// dt/u recomputed in B (268 MFLOP chip-wide) instead of spilled — zero
// extra HBM traffic. GEMMs (MFMA 128x128, R11-verified) unchanged.
// ws layout (bytes):
//   [0)         meanDv                          pad 256
//   [256)       XB  : 8192x1024 bf16 = 16,777,216
//   [16777472)  WIB : 4096x1024 bf16 =  8,388,608
//   [25166080)  WOB : 1024x2048 bf16 =  4,194,304
//   [29360384)  XIN : 8192x2048 bf16 = 33,554,432
//   [62914816)  ZG  : 8192x2048 bf16 = 33,554,432
//   [96469248)  APROD: B*P*DI*DS f32 =  8,388,608
//   [104857856) HEND :               =  8,388,608
//   [113246464) HINIT:               =  8,388,608   total 121,635,072 B

using bf16 = __hip_bfloat16;
typedef __attribute__((ext_vector_type(8))) __bf16 bf16x8;
typedef __attribute__((ext_vector_type(4))) float f32x4;

static constexpr int Bdim = 4;
static constexpr int Tdim = 2048;
static constexpr int DM   = 1024;
static constexpr int DI   = 2048;
static constexpr int DS   = 16;
static constexpr int DC   = 4;
static constexpr int DTR  = 32;
static constexpr int Mrows = Bdim * Tdim;   // 8192
static constexpr int P    = 16;             // scan chunks per batch
static constexpr int TC2  = Tdim / P;       // 128 steps per chunk

__device__ __forceinline__ float b2f(bf16 v) { return __bfloat162float(v); }
__device__ __forceinline__ bf16  f2b(float v) { return __float2bfloat16(v); }
__device__ __forceinline__ float silu_f(float v) { return v / (1.0f + __expf(-v)); }
__device__ __forceinline__ float softplus_f(float v) {
  return (v > 15.0f) ? v : log1pf(__expf(v));
}

#define GLOAD_LDS16(gp, lp)                                                  \
  __builtin_amdgcn_global_load_lds(                                          \
      (const __attribute__((address_space(1))) uint32_t*)(gp),               \
      (__attribute__((address_space(3))) uint32_t*)(lp), 16, 0, 0)

// --------------------------------------------------------------------------
__global__ __launch_bounds__(256)
void kmean(const float* __restrict__ Dv, float* __restrict__ meanp) {
  __shared__ float red[256];
  float s = 0.0f;
  for (int i = threadIdx.x; i < DI; i += 256) s += Dv[i];
  red[threadIdx.x] = s;
  __syncthreads();
  for (int o = 128; o > 0; o >>= 1) {
    if (threadIdx.x < o) red[threadIdx.x] += red[threadIdx.x + o];
    __syncthreads();
  }
  if (threadIdx.x == 0) *meanp = red[0] / (float)DI;
}

// fp32 -> bf16 bulk convert, 8 elems/thread
__device__ __forceinline__ unsigned pack2(float x, float y) {
  return (unsigned)__builtin_bit_cast(unsigned short, f2b(x)) |
         ((unsigned)__builtin_bit_cast(unsigned short, f2b(y)) << 16);
}
__global__ __launch_bounds__(256)
void kcvt(const float* __restrict__ src, bf16* __restrict__ dst, int n8) {
  const int i = blockIdx.x * 256 + threadIdx.x;
  if (i >= n8) return;
  const float4 a = reinterpret_cast<const float4*>(src)[2 * i];
  const float4 b = reinterpret_cast<const float4*>(src)[2 * i + 1];
  uint4 v;
  v.x = pack2(a.x, a.y); v.y = pack2(a.z, a.w);
  v.z = pack2(b.x, b.y); v.w = pack2(b.z, b.w);
  reinterpret_cast<uint4*>(dst)[i] = v;
}

// --------------------------------------------------------------------------
// k1: xz = x @ Wi^T + bi  (bf16 MFMA, fp32 acc). Grid (32,64).
// --------------------------------------------------------------------------
__global__ __launch_bounds__(256)
void k1(const bf16* __restrict__ A, const bf16* __restrict__ W,
        const float* __restrict__ bi,
        bf16* __restrict__ XIN, bf16* __restrict__ ZG)
{
  __shared__ bf16 Al[128 * 32];
  __shared__ bf16 Bl[128 * 32];
  const int tid  = threadIdx.x;
  const int bm   = blockIdx.y * 128;
  const int bn   = blockIdx.x * 128;
  const int lane = tid & 63, wid = tid >> 6;
  const int wr = wid >> 1, wc = wid & 1;
  const int fr = lane & 15;
  const int kg = (lane >> 4) * 8;
  const int ldr = tid >> 2, ldc = (tid & 3) * 8;
  constexpr int K = DM;

  const bf16* ga = A + (size_t)(bm + ldr) * K + ldc;
  const bf16* gb = W + (size_t)(bn + ldr) * K + ldc;

  f32x4 acc[4][4];
#pragma unroll
  for (int i = 0; i < 4; ++i)
#pragma unroll
    for (int j = 0; j < 4; ++j) acc[i][j] = (f32x4){0.f, 0.f, 0.f, 0.f};

  for (int k0 = 0; k0 < K; k0 += 32) {
    GLOAD_LDS16(ga + k0,          &Al[tid * 8]);
    GLOAD_LDS16(ga + k0 + 64 * K, &Al[2048 + tid * 8]);
    GLOAD_LDS16(gb + k0,          &Bl[tid * 8]);
    GLOAD_LDS16(gb + k0 + 64 * K, &Bl[2048 + tid * 8]);
    asm volatile("s_waitcnt vmcnt(0)" ::: "memory");
    __syncthreads();
    bf16x8 af[4], bfr[4];
#pragma unroll
    for (int i = 0; i < 4; ++i)
      af[i]  = *(const bf16x8*)&Al[(wr * 64 + i * 16 + fr) * 32 + kg];
#pragma unroll
    for (int j = 0; j < 4; ++j)
      bfr[j] = *(const bf16x8*)&Bl[(wc * 64 + j * 16 + fr) * 32 + kg];
#pragma unroll
    for (int i = 0; i < 4; ++i)
#pragma unroll
      for (int j = 0; j < 4; ++j)
        acc[i][j] = __builtin_amdgcn_mfma_f32_16x16x32_bf16(
            af[i], bfr[j], acc[i][j], 0, 0, 0);
    __syncthreads();
  }

  const int r0 = (lane >> 4) * 4;
#pragma unroll
  for (int j = 0; j < 4; ++j) {
    const int col = bn + wc * 64 + j * 16 + fr;
    const float bv = bi[col];
    const bool isx = (col < DI);           // wave-uniform (64-aligned split)
#pragma unroll
    for (int i = 0; i < 4; ++i) {
      const int rowb = bm + wr * 64 + i * 16 + r0;
#pragma unroll
      for (int r = 0; r < 4; ++r) {
        const float v = acc[i][j][r] + bv;
        if (isx) XIN[(size_t)(rowb + r) * DI + col]        = f2b(v);
        else     ZG [(size_t)(rowb + r) * DI + (col - DI)] = f2b(silu_f(v));
      }
    }
  }
}

// --------------------------------------------------------------------------
// kscanA: per-chunk local scan from h=0. Emits A_c (decay product) + h_end.
// Grid (DI/16, Bdim*P), 256 thr = 16d x 16n.
// --------------------------------------------------------------------------
__global__ __launch_bounds__(256)
void kscanA(const bf16* __restrict__ XIN,
            const float* __restrict__ cw, const float* __restrict__ cb,
            const float* __restrict__ Wdt, const float* __restrict__ bdt,
            const float* __restrict__ A_log, const float* __restrict__ Bm,
            float* __restrict__ APROD, float* __restrict__ HEND)
{
  __shared__ float Wl[16][33];
  __shared__ float x32[64][33];
  __shared__ float xc[67][17];
  __shared__ float dts[16][68];
  __shared__ float us [16][68];

  const int tid = threadIdx.x;
  const int n  = tid & 15;
  const int dl = tid >> 4;
  const int d0 = blockIdx.x * 16;
  const int d  = d0 + dl;
  const int b  = blockIdx.y / P;
  const int c  = blockIdx.y % P;
  const size_t rbase = (size_t)b * Tdim;
  const int tstart = c * TC2;

  const float Af = -__expf(A_log[(size_t)d * DS + n]);
  const float Bf = Bm[(size_t)d * DS + n];
  const float w0 = cw[d * DC + 0], w1 = cw[d * DC + 1];
  const float w2 = cw[d * DC + 2], w3 = cw[d * DC + 3];
  const float c0 = cb[d];
  const float bdtv = bdt[d];

  for (int e = tid; e < 16 * DTR; e += 256)
    Wl[e >> 5][e & 31] = Wdt[(size_t)(d0 + (e >> 5)) * DTR + (e & 31)];

  float h = 0.0f;
  float p = 1.0f;

  for (int t0 = tstart; t0 < tstart + TC2; t0 += 64) {
    __syncthreads();
    for (int e = tid; e < 64 * 32; e += 256) {
      const int tl = e >> 5, r = e & 31;
      x32[tl][r] = b2f(XIN[(rbase + t0 + tl) * DI + r]);
    }
    for (int e = tid; e < 67 * 16; e += 256) {
      const int i = e >> 4, dd = e & 15;
      const int rr = t0 + i - 3;
      xc[i][dd] = (rr < 0) ? 0.0f : b2f(XIN[(rbase + rr) * DI + d0 + dd]);
    }
    __syncthreads();

#pragma unroll
    for (int q = 0; q < 4; ++q) {
      const int tl = n + 16 * q;
      const float cv = c0 + w0 * xc[tl][dl] + w1 * xc[tl + 1][dl]
                          + w2 * xc[tl + 2][dl] + w3 * xc[tl + 3][dl];
      us[dl][tl] = silu_f(cv);
      float a = bdtv;
#pragma unroll
      for (int r = 0; r < DTR; ++r) a += x32[tl][r] * Wl[dl][r];
      dts[dl][tl] = softplus_f(a);
    }
    __syncthreads();

#pragma unroll 4
    for (int tq = 0; tq < 16; ++tq) {
      const float4 dv = *(const float4*)&dts[dl][4 * tq];
      const float4 uv = *(const float4*)&us [dl][4 * tq];
#define SCAN_STEP_A(DT, UU)                                                   \
      {                                                                       \
        const float dtv = (DT);                                               \
        const float ev  = __expf(dtv * Af);                                   \
        h = h * ev + (dtv * Bf) * (UU);                                       \
        p *= ev;                                                              \
      }
      SCAN_STEP_A(dv.x, uv.x);
      SCAN_STEP_A(dv.y, uv.y);
      SCAN_STEP_A(dv.z, uv.z);
      SCAN_STEP_A(dv.w, uv.w);
#undef SCAN_STEP_A
    }
  }

  const size_t si = (size_t)blockIdx.y * DI * DS + (size_t)d * DS + n;
  APROD[si] = p;
  HEND [si] = h;
}

// --------------------------------------------------------------------------
// kscanH: sequential combine over chunks -> per-chunk initial states.
// One thread per (b, d, n). Grid 512 x 256.
// --------------------------------------------------------------------------
__global__ __launch_bounds__(256)
void kscanH(const float* __restrict__ APROD, const float* __restrict__ HEND,
            float* __restrict__ HINIT)
{
  const int idx = blockIdx.x * 256 + threadIdx.x;   // b*DI*DS + dn
  const int b  = idx / (DI * DS);
  const int dn = idx % (DI * DS);
  float H = 0.0f;
#pragma unroll
  for (int c = 0; c < P; ++c) {
    const size_t si = (size_t)(b * P + c) * DI * DS + dn;
    HINIT[si] = H;
    H = APROD[si] * H + HEND[si];
  }
}

// --------------------------------------------------------------------------
// kscanB: per-chunk scan seeded with HINIT; computes y (DPP suffix-sum)
// and gates ZG in place. Grid (DI/16, Bdim*P).
// --------------------------------------------------------------------------
__global__ __launch_bounds__(256)
void kscanB(const bf16* __restrict__ XIN, bf16* __restrict__ ZG,
            const float* __restrict__ cw, const float* __restrict__ cb,
            const float* __restrict__ Wdt, const float* __restrict__ bdt,
            const float* __restrict__ A_log, const float* __restrict__ Bm,
            const float* __restrict__ Cm, const float* __restrict__ HINIT)
{
  __shared__ float Wl[16][33];
  __shared__ float x32[64][33];
  __shared__ float xc[67][17];
  __shared__ float dts[16][68];
  __shared__ float us [16][68];
  __shared__ float ys [16][68];

  const int tid = threadIdx.x;
  const int n  = tid & 15;
  const int dl = tid >> 4;
  const int d0 = blockIdx.x * 16;
  const int d  = d0 + dl;
  const int b  = blockIdx.y / P;
  const int c  = blockIdx.y % P;
  const size_t rbase = (size_t)b * Tdim;
  const int tstart = c * TC2;

  const float Af = -__expf(A_log[(size_t)d * DS + n]);
  const float Bf = Bm[(size_t)d * DS + n];
  const float Cf = Cm[(size_t)d * DS + n];
  const float w0 = cw[d * DC + 0], w1 = cw[d * DC + 1];
  const float w2 = cw[d * DC + 2], w3 = cw[d * DC + 3];
  const float c0 = cb[d];
  const float bdtv = bdt[d];

  for (int e = tid; e < 16 * DTR; e += 256)
    Wl[e >> 5][e & 31] = Wdt[(size_t)(d0 + (e >> 5)) * DTR + (e & 31)];

  float h = HINIT[(size_t)blockIdx.y * DI * DS + (size_t)d * DS + n];

  for (int t0 = tstart; t0 < tstart + TC2; t0 += 64) {
    __syncthreads();
    for (int e = tid; e < 64 * 32; e += 256) {
      const int tl = e >> 5, r = e & 31;
      x32[tl][r] = b2f(XIN[(rbase + t0 + tl) * DI + r]);
    }
    for (int e = tid; e < 67 * 16; e += 256) {
      const int i = e >> 4, dd = e & 15;
      const int rr = t0 + i - 3;
      xc[i][dd] = (rr < 0) ? 0.0f : b2f(XIN[(rbase + rr) * DI + d0 + dd]);
    }
    __syncthreads();

#pragma unroll
    for (int q = 0; q < 4; ++q) {
      const int tl = n + 16 * q;
      const float cv = c0 + w0 * xc[tl][dl] + w1 * xc[tl + 1][dl]
                          + w2 * xc[tl + 2][dl] + w3 * xc[tl + 3][dl];
      us[dl][tl] = silu_f(cv);
      float a = bdtv;
#pragma unroll
      for (int r = 0; r < DTR; ++r) a += x32[tl][r] * Wl[dl][r];
      dts[dl][tl] = softplus_f(a);
    }
    __syncthreads();

#pragma unroll 4
    for (int tq = 0; tq < 16; ++tq) {
      const float4 dv = *(const float4*)&dts[dl][4 * tq];
      const float4 uv = *(const float4*)&us [dl][4 * tq];
#define SCAN_STEP(DT, UU, TL)                                                 \
      {                                                                       \
        const float dtv = (DT);                                               \
        h = h * __expf(dtv * Af) + (dtv * Bf) * (UU);                         \
        float y = h * Cf;                                                     \
        y += __int_as_float(__builtin_amdgcn_update_dpp(                      \
                 0, __float_as_int(y), 0x111, 0xf, 0xf, true));               \
        y += __int_as_float(__builtin_amdgcn_update_dpp(                      \
                 0, __float_as_int(y), 0x112, 0xf, 0xf, true));               \
        y += __int_as_float(__builtin_amdgcn_update_dpp(                      \
                 0, __float_as_int(y), 0x114, 0xf, 0xf, true));               \
        y += __int_as_float(__builtin_amdgcn_update_dpp(                      \
                 0, __float_as_int(y), 0x118, 0xf, 0xf, true));               \
        if (n == 15) ys[dl][TL] = y;                                          \
      }
      SCAN_STEP(dv.x, uv.x, 4 * tq + 0);
      SCAN_STEP(dv.y, uv.y, 4 * tq + 1);
      SCAN_STEP(dv.z, uv.z, 4 * tq + 2);
      SCAN_STEP(dv.w, uv.w, 4 * tq + 3);
#undef SCAN_STEP
    }
    __syncthreads();

    for (int e = tid; e < 64 * 16; e += 256) {
      const int tl = e >> 4, dd = e & 15;
      const size_t gi = (rbase + t0 + tl) * DI + d0 + dd;
      ZG[gi] = f2b(ys[dd][tl] * b2f(ZG[gi]));
    }
  }
}

// --------------------------------------------------------------------------
// k2: out = G @ Wo^T + bo + meanDv*x  (bf16 MFMA, fp32 acc, pure store).
// --------------------------------------------------------------------------
__global__ __launch_bounds__(256)
void k2(const bf16* __restrict__ G, const bf16* __restrict__ W,
        const float* __restrict__ x, const float* __restrict__ bo,
        const float* __restrict__ meanp, float* __restrict__ out)
{
  __shared__ bf16 Al[128 * 32];
  __shared__ bf16 Bl[128 * 32];
  const int tid  = threadIdx.x;
  const int bm   = blockIdx.y * 128;
  const int bn   = blockIdx.x * 128;
  const int lane = tid & 63, wid = tid >> 6;
  const int wr = wid >> 1, wc = wid & 1;
  const int fr = lane & 15;
  const int kg = (lane >> 4) * 8;
  const int ldr = tid >> 2, ldc = (tid & 3) * 8;
  constexpr int K = DI;

  const bf16* ga = G + (size_t)(bm + ldr) * K + ldc;
  const bf16* gb = W + (size_t)(bn + ldr) * K + ldc;
  const float mv = *meanp;

  f32x4 acc[4][4];
#pragma unroll
  for (int i = 0; i < 4; ++i)
#pragma unroll
    for (int j = 0; j < 4; ++j) acc[i][j] = (f32x4){0.f, 0.f, 0.f, 0.f};

  for (int k0 = 0; k0 < K; k0 += 32) {
    GLOAD_LDS16(ga + k0,          &Al[tid * 8]);
    GLOAD_LDS16(ga + k0 + 64 * K, &Al[2048 + tid * 8]);
    GLOAD_LDS16(gb + k0,          &Bl[tid * 8]);
    GLOAD_LDS16(gb + k0 + 64 * K, &Bl[2048 + tid * 8]);
    asm volatile("s_waitcnt vmcnt(0)" ::: "memory");
    __syncthreads();
    bf16x8 af[4], bfr[4];
#pragma unroll
    for (int i = 0; i < 4; ++i)
      af[i]  = *(const bf16x8*)&Al[(wr * 64 + i * 16 + fr) * 32 + kg];
#pragma unroll
    for (int j = 0; j < 4; ++j)
      bfr[j] = *(const bf16x8*)&Bl[(wc * 64 + j * 16 + fr) * 32 + kg];
#pragma unroll
    for (int i = 0; i < 4; ++i)
#pragma unroll
      for (int j = 0; j < 4; ++j)
        acc[i][j] = __builtin_amdgcn_mfma_f32_16x16x32_bf16(
            af[i], bfr[j], acc[i][j], 0, 0, 0);
    __syncthreads();
  }

  const int r0 = (lane >> 4) * 4;
#pragma unroll
  for (int j = 0; j < 4; ++j) {
    const int col = bn + wc * 64 + j * 16 + fr;
    const float bv = bo[col];
#pragma unroll
    for (int i = 0; i < 4; ++i) {
      const int rowb = bm + wr * 64 + i * 16 + r0;
#pragma unroll
      for (int r = 0; r < 4; ++r) {
        const size_t oi = (size_t)(rowb + r) * DM + col;
        out[oi] = acc[i][j][r] + bv + mv * x[oi];
      }
    }
  }
}

// --------------------------------------------------------------------------
extern "C" void kernel_launch(void* const* d_in, const int* in_sizes, int n_in,
                              void* d_out, int out_size, void* d_ws, size_t ws_size,
                              hipStream_t stream)
{
  const float* x    = (const float*)d_in[0];
  const float* Wi   = (const float*)d_in[1];
  const float* bi   = (const float*)d_in[2];
  const float* cw   = (const float*)d_in[3];
  const float* cb   = (const float*)d_in[4];
  const float* Wdt  = (const float*)d_in[5];
  const float* bdt  = (const float*)d_in[6];
  const float* Alog = (const float*)d_in[7];
  const float* Bm   = (const float*)d_in[8];
  const float* Cm   = (const float*)d_in[9];
  const float* Dv   = (const float*)d_in[10];
  const float* Wo   = (const float*)d_in[11];
  const float* bo   = (const float*)d_in[12];
  float* out = (float*)d_out;

  char* ws = (char*)d_ws;
  float* MEANP = (float*)(ws);
  bf16*  XB    = (bf16*)(ws + 256);
  bf16*  WIB   = (bf16*)(ws + 16777472);
  bf16*  WOB   = (bf16*)(ws + 25166080);
  bf16*  XIN   = (bf16*)(ws + 29360384);
  bf16*  ZG    = (bf16*)(ws + 62914816);
  float* APROD = (float*)(ws + 96469248);
  float* HEND  = (float*)(ws + 104857856);
  float* HINIT = (float*)(ws + 113246464);
  // total ws use: 121,635,072 B

  kmean<<<1, 256, 0, stream>>>(Dv, MEANP);
  kcvt<<<Mrows * DM / 8 / 256, 256, 0, stream>>>(x,  XB,  Mrows * DM / 8);
  kcvt<<<2 * DI * DM / 8 / 256, 256, 0, stream>>>(Wi, WIB, 2 * DI * DM / 8);
  kcvt<<<DM * DI / 8 / 256, 256, 0, stream>>>(Wo, WOB, DM * DI / 8);

  k1<<<dim3(2 * DI / 128, Mrows / 128), 256, 0, stream>>>(XB, WIB, bi, XIN, ZG);

  kscanA<<<dim3(DI / 16, Bdim * P), 256, 0, stream>>>(
      XIN, cw, cb, Wdt, bdt, Alog, Bm, APROD, HEND);
  kscanH<<<dim3(Bdim * DI * DS / 256), 256, 0, stream>>>(APROD, HEND, HINIT);
  kscanB<<<dim3(DI / 16, Bdim * P), 256, 0, stream>>>(
      XIN, ZG, cw, cb, Wdt, bdt, Alog, Bm, Cm, HINIT);

  k2<<<dim3(DM / 128, Mrows / 128), 256, 0, stream>>>(ZG, WOB, x, bo, MEANP, out);
}

// Round 4
// 571.518 us; speedup vs baseline: 1.1795x; 1.1795x over previous
//
#include <hip/hip_runtime.h>
#include <hip/hip_bf16.h>
#include <math.h>
#include <stdint.h>

// SimpleSSMLayer on gfx950 — Round 13: MFMA-dt + de-serialized kscanA.
// R12 counters: kscanA+B = 515/674 us, VALUBusy 83%, VGPR=52 — issue-bound;
// audit: dt-GEMV = 32x(2 ds_read + fma)x4 = 384 inst/thread/block (nothing
// hoisted), serial exp chain 15 inst/step. This round:
//   * dt = x[:, :32] @ Wdt^T via ONE mfma_f32_16x16x32_bf16 per wave per
//     64-t block (A-frag direct from global XIN, L2-hot; Wdt pre-cvt bf16).
//     Drops GEMV + x32 tile + Wl tile from both scan kernels.
//   * kscanA: NO serial scan. HEND = sum_s exp((S_L-S_s)Af)*f_s via backward
//     suffix-sum R (exponents <= 0, overflow-free); APROD = exp(R_final*Af).
//     ~6 inst/step, no dependent exp chain.
//   * kscanB: seeded serial scan kept; y batched into float4, one masked
//     ds_write_b128 per 4 steps.
// GEMMs k1/k2 (MFMA 128x128, verified) unchanged.
// ws layout (bytes):
//   [0)         meanDv                          pad 256
//   [256)       XB  : 8192x1024 bf16 = 16,777,216
//   [16777472)  WIB : 4096x1024 bf16 =  8,388,608
//   [25166080)  WOB : 1024x2048 bf16 =  4,194,304
//   [29360384)  XIN : 8192x2048 bf16 = 33,554,432
//   [62914816)  ZG  : 8192x2048 bf16 = 33,554,432
//   [96469248)  APROD: B*P*DI*DS f32 =  8,388,608
//   [104857856) HEND :               =  8,388,608
//   [113246464) HINIT:               =  8,388,608
//   [121635072) WDTB: 2048x32 bf16   =    131,072   total 121,766,144 B

using bf16 = __hip_bfloat16;
typedef __attribute__((ext_vector_type(8))) __bf16 bf16x8;
typedef __attribute__((ext_vector_type(4))) float f32x4;

static constexpr int Bdim = 4;
static constexpr int Tdim = 2048;
static constexpr int DM   = 1024;
static constexpr int DI   = 2048;
static constexpr int DS   = 16;
static constexpr int DC   = 4;
static constexpr int DTR  = 32;
static constexpr int Mrows = Bdim * Tdim;   // 8192
static constexpr int P    = 16;             // scan chunks per batch
static constexpr int TC2  = Tdim / P;       // 128 steps per chunk

__device__ __forceinline__ float b2f(bf16 v) { return __bfloat162float(v); }
__device__ __forceinline__ bf16  f2b(float v) { return __float2bfloat16(v); }
__device__ __forceinline__ float silu_f(float v) { return v / (1.0f + __expf(-v)); }
__device__ __forceinline__ float softplus_f(float v) {
  return (v > 15.0f) ? v : log1pf(__expf(v));
}

#define GLOAD_LDS16(gp, lp)                                                  \
  __builtin_amdgcn_global_load_lds(                                          \
      (const __attribute__((address_space(1))) uint32_t*)(gp),               \
      (__attribute__((address_space(3))) uint32_t*)(lp), 16, 0, 0)

// --------------------------------------------------------------------------
__global__ __launch_bounds__(256)
void kmean(const float* __restrict__ Dv, float* __restrict__ meanp) {
  __shared__ float red[256];
  float s = 0.0f;
  for (int i = threadIdx.x; i < DI; i += 256) s += Dv[i];
  red[threadIdx.x] = s;
  __syncthreads();
  for (int o = 128; o > 0; o >>= 1) {
    if (threadIdx.x < o) red[threadIdx.x] += red[threadIdx.x + o];
    __syncthreads();
  }
  if (threadIdx.x == 0) *meanp = red[0] / (float)DI;
}

// fp32 -> bf16 bulk convert, 8 elems/thread
__device__ __forceinline__ unsigned pack2(float x, float y) {
  return (unsigned)__builtin_bit_cast(unsigned short, f2b(x)) |
         ((unsigned)__builtin_bit_cast(unsigned short, f2b(y)) << 16);
}
__global__ __launch_bounds__(256)
void kcvt(const float* __restrict__ src, bf16* __restrict__ dst, int n8) {
  const int i = blockIdx.x * 256 + threadIdx.x;
  if (i >= n8) return;
  const float4 a = reinterpret_cast<const float4*>(src)[2 * i];
  const float4 b = reinterpret_cast<const float4*>(src)[2 * i + 1];
  uint4 v;
  v.x = pack2(a.x, a.y); v.y = pack2(a.z, a.w);
  v.z = pack2(b.x, b.y); v.w = pack2(b.z, b.w);
  reinterpret_cast<uint4*>(dst)[i] = v;
}

// --------------------------------------------------------------------------
// k1: xz = x @ Wi^T + bi  (bf16 MFMA, fp32 acc). Grid (32,64).
// --------------------------------------------------------------------------
__global__ __launch_bounds__(256)
void k1(const bf16* __restrict__ A, const bf16* __restrict__ W,
        const float* __restrict__ bi,
        bf16* __restrict__ XIN, bf16* __restrict__ ZG)
{
  __shared__ bf16 Al[128 * 32];
  __shared__ bf16 Bl[128 * 32];
  const int tid  = threadIdx.x;
  const int bm   = blockIdx.y * 128;
  const int bn   = blockIdx.x * 128;
  const int lane = tid & 63, wid = tid >> 6;
  const int wr = wid >> 1, wc = wid & 1;
  const int fr = lane & 15;
  const int kg = (lane >> 4) * 8;
  const int ldr = tid >> 2, ldc = (tid & 3) * 8;
  constexpr int K = DM;

  const bf16* ga = A + (size_t)(bm + ldr) * K + ldc;
  const bf16* gb = W + (size_t)(bn + ldr) * K + ldc;

  f32x4 acc[4][4];
#pragma unroll
  for (int i = 0; i < 4; ++i)
#pragma unroll
    for (int j = 0; j < 4; ++j) acc[i][j] = (f32x4){0.f, 0.f, 0.f, 0.f};

  for (int k0 = 0; k0 < K; k0 += 32) {
    GLOAD_LDS16(ga + k0,          &Al[tid * 8]);
    GLOAD_LDS16(ga + k0 + 64 * K, &Al[2048 + tid * 8]);
    GLOAD_LDS16(gb + k0,          &Bl[tid * 8]);
    GLOAD_LDS16(gb + k0 + 64 * K, &Bl[2048 + tid * 8]);
    asm volatile("s_waitcnt vmcnt(0)" ::: "memory");
    __syncthreads();
    bf16x8 af[4], bfr[4];
#pragma unroll
    for (int i = 0; i < 4; ++i)
      af[i]  = *(const bf16x8*)&Al[(wr * 64 + i * 16 + fr) * 32 + kg];
#pragma unroll
    for (int j = 0; j < 4; ++j)
      bfr[j] = *(const bf16x8*)&Bl[(wc * 64 + j * 16 + fr) * 32 + kg];
#pragma unroll
    for (int i = 0; i < 4; ++i)
#pragma unroll
      for (int j = 0; j < 4; ++j)
        acc[i][j] = __builtin_amdgcn_mfma_f32_16x16x32_bf16(
            af[i], bfr[j], acc[i][j], 0, 0, 0);
    __syncthreads();
  }

  const int r0 = (lane >> 4) * 4;
#pragma unroll
  for (int j = 0; j < 4; ++j) {
    const int col = bn + wc * 64 + j * 16 + fr;
    const float bv = bi[col];
    const bool isx = (col < DI);           // wave-uniform (64-aligned split)
#pragma unroll
    for (int i = 0; i < 4; ++i) {
      const int rowb = bm + wr * 64 + i * 16 + r0;
#pragma unroll
      for (int r = 0; r < 4; ++r) {
        const float v = acc[i][j][r] + bv;
        if (isx) XIN[(size_t)(rowb + r) * DI + col]        = f2b(v);
        else     ZG [(size_t)(rowb + r) * DI + (col - DI)] = f2b(silu_f(v));
      }
    }
  }
}

// --------------------------------------------------------------------------
// kscanA: per-chunk. dt via MFMA, u via conv; HEND via backward suffix-sum
// (no serial chain); APROD = exp(S_L * Af). Grid (DI/16, Bdim*P).
// --------------------------------------------------------------------------
__global__ __launch_bounds__(256)
void kscanA(const bf16* __restrict__ XIN, const bf16* __restrict__ WDTB,
            const float* __restrict__ cw, const float* __restrict__ cb,
            const float* __restrict__ bdt,
            const float* __restrict__ A_log, const float* __restrict__ Bm,
            float* __restrict__ APROD, float* __restrict__ HEND)
{
  __shared__ float xc[67][17];
  __shared__ float dts[16][68];   // [d][t]
  __shared__ float us [16][68];

  const int tid  = threadIdx.x;
  const int lane = tid & 63;
  const int wid  = tid >> 6;
  const int n  = tid & 15;
  const int dl = tid >> 4;
  const int d0 = blockIdx.x * 16;
  const int d  = d0 + dl;
  const int b  = blockIdx.y / P;
  const int c  = blockIdx.y % P;
  const size_t rbase = (size_t)b * Tdim;
  const int tstart = c * TC2;

  const int fr = lane & 15;
  const int kg = (lane >> 4) * 8;
  const float bdtf = bdt[d0 + fr];                 // MFMA epilogue bias
  const bf16x8 wfrag = *(const bf16x8*)&WDTB[(size_t)(d0 + fr) * DTR + kg];

  const float Af = -__expf(A_log[(size_t)d * DS + n]);
  const float Bf = Bm[(size_t)d * DS + n];
  const float w0 = cw[d * DC + 0], w1 = cw[d * DC + 1];
  const float w2 = cw[d * DC + 2], w3 = cw[d * DC + 3];
  const float c0 = cb[d];

  float acc = 0.0f;   // HEND accumulator
  float R   = 0.0f;   // suffix dt sum

  // process 64-t halves in REVERSE so R runs over the whole chunk
  for (int t0 = tstart + TC2 - 64; t0 >= tstart; t0 -= 64) {
    __syncthreads();
    for (int e = tid; e < 67 * 16; e += 256) {     // conv window
      const int i = e >> 4, dd = e & 15;
      const int rr = t0 + i - 3;
      xc[i][dd] = (rr < 0) ? 0.0f : b2f(XIN[(rbase + rr) * DI + d0 + dd]);
    }
    {                                              // dt = x@Wdt^T via MFMA
      const bf16x8 xfrag =
          *(const bf16x8*)&XIN[(rbase + t0 + wid * 16 + fr) * DI + kg];
      f32x4 a = (f32x4){0.f, 0.f, 0.f, 0.f};
      a = __builtin_amdgcn_mfma_f32_16x16x32_bf16(xfrag, wfrag, a, 0, 0, 0);
      float4 dq;
      dq.x = softplus_f(a[0] + bdtf);
      dq.y = softplus_f(a[1] + bdtf);
      dq.z = softplus_f(a[2] + bdtf);
      dq.w = softplus_f(a[3] + bdtf);
      *(float4*)&dts[fr][wid * 16 + (lane >> 4) * 4] = dq;
    }
    __syncthreads();
#pragma unroll
    for (int q = 0; q < 4; ++q) {                  // conv + silu -> u
      const int tl = n + 16 * q;
      const float cv = c0 + w0 * xc[tl][dl] + w1 * xc[tl + 1][dl]
                          + w2 * xc[tl + 2][dl] + w3 * xc[tl + 3][dl];
      us[dl][tl] = silu_f(cv);
    }
    __syncthreads();
    // backward independent-term sum (s descending within this half)
#pragma unroll 4
    for (int sq = 15; sq >= 0; --sq) {
      const float4 dv = *(const float4*)&dts[dl][4 * sq];
      const float4 uv = *(const float4*)&us [dl][4 * sq];
#define ASTEP(DT, UU)                                                         \
      {                                                                       \
        acc += __expf(R * Af) * (((DT) * Bf) * (UU));                         \
        R += (DT);                                                            \
      }
      ASTEP(dv.w, uv.w); ASTEP(dv.z, uv.z); ASTEP(dv.y, uv.y); ASTEP(dv.x, uv.x);
#undef ASTEP
    }
  }

  const size_t si = (size_t)blockIdx.y * DI * DS + (size_t)d * DS + n;
  APROD[si] = __expf(R * Af);
  HEND [si] = acc;
}

// --------------------------------------------------------------------------
// kscanH: sequential combine over chunks -> per-chunk initial states.
// --------------------------------------------------------------------------
__global__ __launch_bounds__(256)
void kscanH(const float* __restrict__ APROD, const float* __restrict__ HEND,
            float* __restrict__ HINIT)
{
  const int idx = blockIdx.x * 256 + threadIdx.x;   // b*DI*DS + dn
  const int b  = idx / (DI * DS);
  const int dn = idx % (DI * DS);
  float H = 0.0f;
#pragma unroll
  for (int c = 0; c < P; ++c) {
    const size_t si = (size_t)(b * P + c) * DI * DS + dn;
    HINIT[si] = H;
    H = APROD[si] * H + HEND[si];
  }
}

// --------------------------------------------------------------------------
// kscanB: per-chunk seeded scan; dt via MFMA, u via conv; y via DPP
// suffix tree, gated into ZG. Grid (DI/16, Bdim*P).
// --------------------------------------------------------------------------
__global__ __launch_bounds__(256)
void kscanB(const bf16* __restrict__ XIN, bf16* __restrict__ ZG,
            const bf16* __restrict__ WDTB,
            const float* __restrict__ cw, const float* __restrict__ cb,
            const float* __restrict__ bdt,
            const float* __restrict__ A_log, const float* __restrict__ Bm,
            const float* __restrict__ Cm, const float* __restrict__ HINIT)
{
  __shared__ float xc[67][17];
  __shared__ float dts[16][68];
  __shared__ float us [16][68];
  __shared__ float ys [16][68];

  const int tid  = threadIdx.x;
  const int lane = tid & 63;
  const int wid  = tid >> 6;
  const int n  = tid & 15;
  const int dl = tid >> 4;
  const int d0 = blockIdx.x * 16;
  const int d  = d0 + dl;
  const int b  = blockIdx.y / P;
  const int c  = blockIdx.y % P;
  const size_t rbase = (size_t)b * Tdim;
  const int tstart = c * TC2;

  const int fr = lane & 15;
  const int kg = (lane >> 4) * 8;
  const float bdtf = bdt[d0 + fr];
  const bf16x8 wfrag = *(const bf16x8*)&WDTB[(size_t)(d0 + fr) * DTR + kg];

  const float Af = -__expf(A_log[(size_t)d * DS + n]);
  const float Bf = Bm[(size_t)d * DS + n];
  const float Cf = Cm[(size_t)d * DS + n];
  const float w0 = cw[d * DC + 0], w1 = cw[d * DC + 1];
  const float w2 = cw[d * DC + 2], w3 = cw[d * DC + 3];
  const float c0 = cb[d];

  float h = HINIT[(size_t)blockIdx.y * DI * DS + (size_t)d * DS + n];

  for (int t0 = tstart; t0 < tstart + TC2; t0 += 64) {
    __syncthreads();
    for (int e = tid; e < 67 * 16; e += 256) {
      const int i = e >> 4, dd = e & 15;
      const int rr = t0 + i - 3;
      xc[i][dd] = (rr < 0) ? 0.0f : b2f(XIN[(rbase + rr) * DI + d0 + dd]);
    }
    {
      const bf16x8 xfrag =
          *(const bf16x8*)&XIN[(rbase + t0 + wid * 16 + fr) * DI + kg];
      f32x4 a = (f32x4){0.f, 0.f, 0.f, 0.f};
      a = __builtin_amdgcn_mfma_f32_16x16x32_bf16(xfrag, wfrag, a, 0, 0, 0);
      float4 dq;
      dq.x = softplus_f(a[0] + bdtf);
      dq.y = softplus_f(a[1] + bdtf);
      dq.z = softplus_f(a[2] + bdtf);
      dq.w = softplus_f(a[3] + bdtf);
      *(float4*)&dts[fr][wid * 16 + (lane >> 4) * 4] = dq;
    }
    __syncthreads();
#pragma unroll
    for (int q = 0; q < 4; ++q) {
      const int tl = n + 16 * q;
      const float cv = c0 + w0 * xc[tl][dl] + w1 * xc[tl + 1][dl]
                          + w2 * xc[tl + 2][dl] + w3 * xc[tl + 3][dl];
      us[dl][tl] = silu_f(cv);
    }
    __syncthreads();

#pragma unroll 4
    for (int tq = 0; tq < 16; ++tq) {
      const float4 dv = *(const float4*)&dts[dl][4 * tq];
      const float4 uv = *(const float4*)&us [dl][4 * tq];
      float4 y4;
#define SCAN_STEP(DT, UU, YS)                                                 \
      {                                                                       \
        const float dtv = (DT);                                               \
        h = h * __expf(dtv * Af) + (dtv * Bf) * (UU);                         \
        float y = h * Cf;                                                     \
        y += __int_as_float(__builtin_amdgcn_update_dpp(                      \
                 0, __float_as_int(y), 0x111, 0xf, 0xf, true));               \
        y += __int_as_float(__builtin_amdgcn_update_dpp(                      \
                 0, __float_as_int(y), 0x112, 0xf, 0xf, true));               \
        y += __int_as_float(__builtin_amdgcn_update_dpp(                      \
                 0, __float_as_int(y), 0x114, 0xf, 0xf, true));               \
        y += __int_as_float(__builtin_amdgcn_update_dpp(                      \
                 0, __float_as_int(y), 0x118, 0xf, 0xf, true));               \
        YS = y;                                                               \
      }
      SCAN_STEP(dv.x, uv.x, y4.x);
      SCAN_STEP(dv.y, uv.y, y4.y);
      SCAN_STEP(dv.z, uv.z, y4.z);
      SCAN_STEP(dv.w, uv.w, y4.w);
#undef SCAN_STEP
      if (n == 15) *(float4*)&ys[dl][4 * tq] = y4;
    }
    __syncthreads();

    for (int e = tid; e < 64 * 16; e += 256) {
      const int tl = e >> 4, dd = e & 15;
      const size_t gi = (rbase + t0 + tl) * DI + d0 + dd;
      ZG[gi] = f2b(ys[dd][tl] * b2f(ZG[gi]));
    }
  }
}

// --------------------------------------------------------------------------
// k2: out = G @ Wo^T + bo + meanDv*x  (bf16 MFMA, fp32 acc, pure store).
// --------------------------------------------------------------------------
__global__ __launch_bounds__(256)
void k2(const bf16* __restrict__ G, const bf16* __restrict__ W,
        const float* __restrict__ x, const float* __restrict__ bo,
        const float* __restrict__ meanp, float* __restrict__ out)
{
  __shared__ bf16 Al[128 * 32];
  __shared__ bf16 Bl[128 * 32];
  const int tid  = threadIdx.x;
  const int bm   = blockIdx.y * 128;
  const int bn   = blockIdx.x * 128;
  const int lane = tid & 63, wid = tid >> 6;
  const int wr = wid >> 1, wc = wid & 1;
  const int fr = lane & 15;
  const int kg = (lane >> 4) * 8;
  const int ldr = tid >> 2, ldc = (tid & 3) * 8;
  constexpr int K = DI;

  const bf16* ga = G + (size_t)(bm + ldr) * K + ldc;
  const bf16* gb = W + (size_t)(bn + ldr) * K + ldc;
  const float mv = *meanp;

  f32x4 acc[4][4];
#pragma unroll
  for (int i = 0; i < 4; ++i)
#pragma unroll
    for (int j = 0; j < 4; ++j) acc[i][j] = (f32x4){0.f, 0.f, 0.f, 0.f};

  for (int k0 = 0; k0 < K; k0 += 32) {
    GLOAD_LDS16(ga + k0,          &Al[tid * 8]);
    GLOAD_LDS16(ga + k0 + 64 * K, &Al[2048 + tid * 8]);
    GLOAD_LDS16(gb + k0,          &Bl[tid * 8]);
    GLOAD_LDS16(gb + k0 + 64 * K, &Bl[2048 + tid * 8]);
    asm volatile("s_waitcnt vmcnt(0)" ::: "memory");
    __syncthreads();
    bf16x8 af[4], bfr[4];
#pragma unroll
    for (int i = 0; i < 4; ++i)
      af[i]  = *(const bf16x8*)&Al[(wr * 64 + i * 16 + fr) * 32 + kg];
#pragma unroll
    for (int j = 0; j < 4; ++j)
      bfr[j] = *(const bf16x8*)&Bl[(wc * 64 + j * 16 + fr) * 32 + kg];
#pragma unroll
    for (int i = 0; i < 4; ++i)
#pragma unroll
      for (int j = 0; j < 4; ++j)
        acc[i][j] = __builtin_amdgcn_mfma_f32_16x16x32_bf16(
            af[i], bfr[j], acc[i][j], 0, 0, 0);
    __syncthreads();
  }

  const int r0 = (lane >> 4) * 4;
#pragma unroll
  for (int j = 0; j < 4; ++j) {
    const int col = bn + wc * 64 + j * 16 + fr;
    const float bv = bo[col];
#pragma unroll
    for (int i = 0; i < 4; ++i) {
      const int rowb = bm + wr * 64 + i * 16 + r0;
#pragma unroll
      for (int r = 0; r < 4; ++r) {
        const size_t oi = (size_t)(rowb + r) * DM + col;
        out[oi] = acc[i][j][r] + bv + mv * x[oi];
      }
    }
  }
}

// --------------------------------------------------------------------------
extern "C" void kernel_launch(void* const* d_in, const int* in_sizes, int n_in,
                              void* d_out, int out_size, void* d_ws, size_t ws_size,
                              hipStream_t stream)
{
  const float* x    = (const float*)d_in[0];
  const float* Wi   = (const float*)d_in[1];
  const float* bi   = (const float*)d_in[2];
  const float* cw   = (const float*)d_in[3];
  const float* cb   = (const float*)d_in[4];
  const float* Wdt  = (const float*)d_in[5];
  const float* bdt  = (const float*)d_in[6];
  const float* Alog = (const float*)d_in[7];
  const float* Bm   = (const float*)d_in[8];
  const float* Cm   = (const float*)d_in[9];
  const float* Dv   = (const float*)d_in[10];
  const float* Wo   = (const float*)d_in[11];
  const float* bo   = (const float*)d_in[12];
  float* out = (float*)d_out;

  char* ws = (char*)d_ws;
  float* MEANP = (float*)(ws);
  bf16*  XB    = (bf16*)(ws + 256);
  bf16*  WIB   = (bf16*)(ws + 16777472);
  bf16*  WOB   = (bf16*)(ws + 25166080);
  bf16*  XIN   = (bf16*)(ws + 29360384);
  bf16*  ZG    = (bf16*)(ws + 62914816);
  float* APROD = (float*)(ws + 96469248);
  float* HEND  = (float*)(ws + 104857856);
  float* HINIT = (float*)(ws + 113246464);
  bf16*  WDTB  = (bf16*)(ws + 121635072);
  // total ws use: 121,766,144 B

  kmean<<<1, 256, 0, stream>>>(Dv, MEANP);
  kcvt<<<Mrows * DM / 8 / 256, 256, 0, stream>>>(x,  XB,  Mrows * DM / 8);
  kcvt<<<2 * DI * DM / 8 / 256, 256, 0, stream>>>(Wi, WIB, 2 * DI * DM / 8);
  kcvt<<<DM * DI / 8 / 256, 256, 0, stream>>>(Wo, WOB, DM * DI / 8);
  kcvt<<<DI * DTR / 8 / 256, 256, 0, stream>>>(Wdt, WDTB, DI * DTR / 8);

  k1<<<dim3(2 * DI / 128, Mrows / 128), 256, 0, stream>>>(XB, WIB, bi, XIN, ZG);

  kscanA<<<dim3(DI / 16, Bdim * P), 256, 0, stream>>>(
      XIN, WDTB, cw, cb, bdt, Alog, Bm, APROD, HEND);
  kscanH<<<dim3(Bdim * DI * DS / 256), 256, 0, stream>>>(APROD, HEND, HINIT);
  kscanB<<<dim3(DI / 16, Bdim * P), 256, 0, stream>>>(
      XIN, ZG, WDTB, cw, cb, bdt, Alog, Bm, Cm, HINIT);

  k2<<<dim3(DM / 128, Mrows / 128), 256, 0, stream>>>(ZG, WOB, x, bo, MEANP, out);
}

// Round 5
// 480.714 us; speedup vs baseline: 1.4023x; 1.1889x over previous
//
#include <hip/hip_runtime.h>
#include <hip/hip_bf16.h>
#include <math.h>
#include <stdint.h>

// SimpleSSMLayer on gfx950 — Round 14: COMPUTE dt/f ONCE (producer/consumer).
// R13 accounting: kscanA ~214, kscanB ~200 us; removing the GEMV from B only
// bought -57 us => the cost is the duplicated FRONT-END (scalar bf16 conv-halo
// staging, conv+silu, MFMA-dt, log1pf-softplus), not the scan math.
//   * kscanA (P=32, 1 tile/block): unchanged math + writes DTg (fp32) and
//     Fg = dt*u (fp32) in d-major [d][row] layout (coalesced). Front-end
//     slimmed: ushort4 xc staging + float4 LDS writes; softplus via
//     __logf(1+__expf(v)) (~6 inst vs log1pf's ~30).
//   * kscanB: pure reader — no staging/conv/MFMA/softplus. Per 4 steps: two
//     broadcast float4 loads (DTg/Fg, L2-hot) + verified serial scan + DPP.
//     LDS 17.9K -> 4.4K. Gate loop = one ushort4 RMW per thread.
//   * P 16->32: B's serial chain 128 -> 64 steps; 16384 blocks.
// GEMMs k1/k2 (MFMA 128x128, verified) unchanged.
// ws layout (bytes):
//   [0)          meanDv                 pad 256
//   [256)        WOB  : 1024x2048 bf16  =  4,194,304
//   [4194560)    XIN  : 8192x2048 bf16  = 33,554,432
//   [37748992)   ZG   : 8192x2048 bf16  = 33,554,432
//   [71303424)   APROD: B*P*DI*DS f32   = 16,777,216
//   [88080640)   HEND :                 = 16,777,216
//   [104857856)  HINIT:                 = 16,777,216
//   [121635072)  WDTB : 2048x32 bf16    =     131,072
//   [121766144)  DTg  : DIxMrows f32    = 67,108,864
//     XB  alias @121766144 (16,777,216)  dead after k1
//     WIB alias @138543360 ( 8,388,608)  dead after k1
//   [188875008)  Fg   : DIxMrows f32    = 67,108,864   total 255,983,872 B

using bf16 = __hip_bfloat16;
typedef __attribute__((ext_vector_type(8))) __bf16 bf16x8;
typedef __attribute__((ext_vector_type(4))) float f32x4;

static constexpr int Bdim = 4;
static constexpr int Tdim = 2048;
static constexpr int DM   = 1024;
static constexpr int DI   = 2048;
static constexpr int DS   = 16;
static constexpr int DC   = 4;
static constexpr int DTR  = 32;
static constexpr int Mrows = Bdim * Tdim;   // 8192
static constexpr int P    = 32;             // scan chunks per batch
static constexpr int TC2  = Tdim / P;       // 64 steps per chunk

__device__ __forceinline__ float b2f(bf16 v) { return __bfloat162float(v); }
__device__ __forceinline__ bf16  f2b(float v) { return __float2bfloat16(v); }
__device__ __forceinline__ float silu_f(float v) { return v / (1.0f + __expf(-v)); }
__device__ __forceinline__ float softplus_f(float v) {
  return (v > 15.0f) ? v : __logf(1.0f + __expf(v));
}
__device__ __forceinline__ float bfbits2f(unsigned short u) {
  return __uint_as_float((unsigned)u << 16);
}

#define GLOAD_LDS16(gp, lp)                                                  \
  __builtin_amdgcn_global_load_lds(                                          \
      (const __attribute__((address_space(1))) uint32_t*)(gp),               \
      (__attribute__((address_space(3))) uint32_t*)(lp), 16, 0, 0)

// --------------------------------------------------------------------------
__global__ __launch_bounds__(256)
void kmean(const float* __restrict__ Dv, float* __restrict__ meanp) {
  __shared__ float red[256];
  float s = 0.0f;
  for (int i = threadIdx.x; i < DI; i += 256) s += Dv[i];
  red[threadIdx.x] = s;
  __syncthreads();
  for (int o = 128; o > 0; o >>= 1) {
    if (threadIdx.x < o) red[threadIdx.x] += red[threadIdx.x + o];
    __syncthreads();
  }
  if (threadIdx.x == 0) *meanp = red[0] / (float)DI;
}

// fp32 -> bf16 bulk convert, 8 elems/thread
__device__ __forceinline__ unsigned pack2(float x, float y) {
  return (unsigned)__builtin_bit_cast(unsigned short, f2b(x)) |
         ((unsigned)__builtin_bit_cast(unsigned short, f2b(y)) << 16);
}
__global__ __launch_bounds__(256)
void kcvt(const float* __restrict__ src, bf16* __restrict__ dst, int n8) {
  const int i = blockIdx.x * 256 + threadIdx.x;
  if (i >= n8) return;
  const float4 a = reinterpret_cast<const float4*>(src)[2 * i];
  const float4 b = reinterpret_cast<const float4*>(src)[2 * i + 1];
  uint4 v;
  v.x = pack2(a.x, a.y); v.y = pack2(a.z, a.w);
  v.z = pack2(b.x, b.y); v.w = pack2(b.z, b.w);
  reinterpret_cast<uint4*>(dst)[i] = v;
}

// --------------------------------------------------------------------------
// k1: xz = x @ Wi^T + bi  (bf16 MFMA, fp32 acc). Grid (32,64).
// --------------------------------------------------------------------------
__global__ __launch_bounds__(256)
void k1(const bf16* __restrict__ A, const bf16* __restrict__ W,
        const float* __restrict__ bi,
        bf16* __restrict__ XIN, bf16* __restrict__ ZG)
{
  __shared__ bf16 Al[128 * 32];
  __shared__ bf16 Bl[128 * 32];
  const int tid  = threadIdx.x;
  const int bm   = blockIdx.y * 128;
  const int bn   = blockIdx.x * 128;
  const int lane = tid & 63, wid = tid >> 6;
  const int wr = wid >> 1, wc = wid & 1;
  const int fr = lane & 15;
  const int kg = (lane >> 4) * 8;
  const int ldr = tid >> 2, ldc = (tid & 3) * 8;
  constexpr int K = DM;

  const bf16* ga = A + (size_t)(bm + ldr) * K + ldc;
  const bf16* gb = W + (size_t)(bn + ldr) * K + ldc;

  f32x4 acc[4][4];
#pragma unroll
  for (int i = 0; i < 4; ++i)
#pragma unroll
    for (int j = 0; j < 4; ++j) acc[i][j] = (f32x4){0.f, 0.f, 0.f, 0.f};

  for (int k0 = 0; k0 < K; k0 += 32) {
    GLOAD_LDS16(ga + k0,          &Al[tid * 8]);
    GLOAD_LDS16(ga + k0 + 64 * K, &Al[2048 + tid * 8]);
    GLOAD_LDS16(gb + k0,          &Bl[tid * 8]);
    GLOAD_LDS16(gb + k0 + 64 * K, &Bl[2048 + tid * 8]);
    asm volatile("s_waitcnt vmcnt(0)" ::: "memory");
    __syncthreads();
    bf16x8 af[4], bfr[4];
#pragma unroll
    for (int i = 0; i < 4; ++i)
      af[i]  = *(const bf16x8*)&Al[(wr * 64 + i * 16 + fr) * 32 + kg];
#pragma unroll
    for (int j = 0; j < 4; ++j)
      bfr[j] = *(const bf16x8*)&Bl[(wc * 64 + j * 16 + fr) * 32 + kg];
#pragma unroll
    for (int i = 0; i < 4; ++i)
#pragma unroll
      for (int j = 0; j < 4; ++j)
        acc[i][j] = __builtin_amdgcn_mfma_f32_16x16x32_bf16(
            af[i], bfr[j], acc[i][j], 0, 0, 0);
    __syncthreads();
  }

  const int r0 = (lane >> 4) * 4;
#pragma unroll
  for (int j = 0; j < 4; ++j) {
    const int col = bn + wc * 64 + j * 16 + fr;
    const float bv = bi[col];
    const bool isx = (col < DI);           // wave-uniform (64-aligned split)
#pragma unroll
    for (int i = 0; i < 4; ++i) {
      const int rowb = bm + wr * 64 + i * 16 + r0;
#pragma unroll
      for (int r = 0; r < 4; ++r) {
        const float v = acc[i][j][r] + bv;
        if (isx) XIN[(size_t)(rowb + r) * DI + col]        = f2b(v);
        else     ZG [(size_t)(rowb + r) * DI + (col - DI)] = f2b(silu_f(v));
      }
    }
  }
}

// --------------------------------------------------------------------------
// kscanA: producer. Per 64-t chunk: conv+dt (MFMA) -> writes DTg/Fg (d-major)
// + chunk summaries APROD (decay product) / HEND (suffix-sum, no serial exp
// chain). Grid (DI/16, Mrows/64) = (128, 128).
// --------------------------------------------------------------------------
__global__ __launch_bounds__(256)
void kscanA(const bf16* __restrict__ XIN, const bf16* __restrict__ WDTB,
            const float* __restrict__ cw, const float* __restrict__ cb,
            const float* __restrict__ bdt,
            const float* __restrict__ A_log, const float* __restrict__ Bm,
            float* __restrict__ APROD, float* __restrict__ HEND,
            float* __restrict__ DTg, float* __restrict__ Fg)
{
  __shared__ float xc[67][20];    // [t-3..t+63][d], 20-pad for float4 writes
  __shared__ float dts[16][68];   // [d][t]
  __shared__ float fs [16][68];   // [d][t], f = dt*u

  const int tid  = threadIdx.x;
  const int lane = tid & 63;
  const int wid  = tid >> 6;
  const int n  = tid & 15;
  const int dl = tid >> 4;
  const int d0 = blockIdx.x * 16;
  const int d  = d0 + dl;
  const int row0 = blockIdx.y * 64;          // global row (chunk start)
  const int b  = row0 >> 11;                 // row0 / Tdim
  const size_t rbase = (size_t)b * Tdim;
  const int t0 = row0 - (int)rbase;          // batch-local chunk start

  const int fr = lane & 15;
  const int kg = (lane >> 4) * 8;
  const float bdtf = bdt[d0 + fr];
  const bf16x8 wfrag = *(const bf16x8*)&WDTB[(size_t)(d0 + fr) * DTR + kg];

  const float Af = -__expf(A_log[(size_t)d * DS + n]);
  const float Bf = Bm[(size_t)d * DS + n];
  const float w0 = cw[d * DC + 0], w1 = cw[d * DC + 1];
  const float w2 = cw[d * DC + 2], w3 = cw[d * DC + 3];
  const float c0 = cb[d];

  // stage conv window, vectorized: 67 rows x 16 d = 268 ushort4 units
  for (int e = tid; e < 67 * 4; e += 256) {
    const int i = e >> 2, p4 = (e & 3) * 4;
    const int rr = t0 + i - 3;
    float4 v;
    if (rr < 0) {
      v = make_float4(0.f, 0.f, 0.f, 0.f);
    } else {
      const ushort4 u =
          *(const ushort4*)&XIN[(rbase + rr) * DI + d0 + p4];
      v = make_float4(bfbits2f(u.x), bfbits2f(u.y), bfbits2f(u.z), bfbits2f(u.w));
    }
    *(float4*)&xc[i][p4] = v;
  }
  {                                          // dt = x[:, :32] @ Wdt^T via MFMA
    const bf16x8 xfrag =
        *(const bf16x8*)&XIN[(rbase + t0 + wid * 16 + fr) * DI + kg];
    f32x4 a = (f32x4){0.f, 0.f, 0.f, 0.f};
    a = __builtin_amdgcn_mfma_f32_16x16x32_bf16(xfrag, wfrag, a, 0, 0, 0);
    float4 dq;
    dq.x = softplus_f(a[0] + bdtf);
    dq.y = softplus_f(a[1] + bdtf);
    dq.z = softplus_f(a[2] + bdtf);
    dq.w = softplus_f(a[3] + bdtf);
    *(float4*)&dts[fr][wid * 16 + (lane >> 4) * 4] = dq;
  }
  __syncthreads();

  // conv + silu -> u; f = dt*u; stream DTg/Fg to global (coalesced)
#pragma unroll
  for (int q = 0; q < 4; ++q) {
    const int tl = n + 16 * q;
    const float cv = c0 + w0 * xc[tl][dl] + w1 * xc[tl + 1][dl]
                        + w2 * xc[tl + 2][dl] + w3 * xc[tl + 3][dl];
    const float uv  = silu_f(cv);
    const float dtv = dts[dl][tl];
    const float fv  = dtv * uv;
    fs[dl][tl] = fv;
    const size_t go = (size_t)(d0 + dl) * Mrows + row0 + tl;
    DTg[go] = dtv;
    Fg [go] = fv;
  }
  __syncthreads();

  // backward suffix-sum over the 64 steps (no dependent exp chain)
  float acc = 0.0f;
  float R   = 0.0f;
#pragma unroll 4
  for (int sq = 15; sq >= 0; --sq) {
    const float4 dv = *(const float4*)&dts[dl][4 * sq];
    const float4 fv = *(const float4*)&fs [dl][4 * sq];
#define ASTEP(DT, FF)                                                         \
    {                                                                         \
      acc += __expf(R * Af) * (Bf * (FF));                                    \
      R += (DT);                                                              \
    }
    ASTEP(dv.w, fv.w); ASTEP(dv.z, fv.z); ASTEP(dv.y, fv.y); ASTEP(dv.x, fv.x);
#undef ASTEP
  }

  const size_t si = (size_t)blockIdx.y * DI * DS + (size_t)d * DS + n;
  APROD[si] = __expf(R * Af);
  HEND [si] = acc;
}

// --------------------------------------------------------------------------
// kscanH: sequential combine over P=32 chunks -> per-chunk initial states.
// --------------------------------------------------------------------------
__global__ __launch_bounds__(256)
void kscanH(const float* __restrict__ APROD, const float* __restrict__ HEND,
            float* __restrict__ HINIT)
{
  const int idx = blockIdx.x * 256 + threadIdx.x;   // b*DI*DS + dn
  const int b  = idx / (DI * DS);
  const int dn = idx % (DI * DS);
  float H = 0.0f;
#pragma unroll
  for (int c = 0; c < P; ++c) {
    const size_t si = (size_t)(b * P + c) * DI * DS + dn;
    HINIT[si] = H;
    H = APROD[si] * H + HEND[si];
  }
}

// --------------------------------------------------------------------------
// kscanB: pure reader. Seeded 64-step serial scan from DTg/Fg (broadcast
// float4 loads), y via DPP suffix tree, vectorized gate RMW on ZG.
// Grid (DI/16, Mrows/64) = (128, 128).
// --------------------------------------------------------------------------
__global__ __launch_bounds__(256)
void kscanB(const float* __restrict__ DTg, const float* __restrict__ Fg,
            bf16* __restrict__ ZG,
            const float* __restrict__ A_log, const float* __restrict__ Bm,
            const float* __restrict__ Cm, const float* __restrict__ HINIT)
{
  __shared__ float ys[16][68];

  const int tid = threadIdx.x;
  const int n  = tid & 15;
  const int dl = tid >> 4;
  const int d0 = blockIdx.x * 16;
  const int d  = d0 + dl;
  const int row0 = blockIdx.y * 64;

  const float Af = -__expf(A_log[(size_t)d * DS + n]);
  const float Bf = Bm[(size_t)d * DS + n];
  const float Cf = Cm[(size_t)d * DS + n];

  float h = HINIT[(size_t)blockIdx.y * DI * DS + (size_t)d * DS + n];

  const size_t base = (size_t)(d0 + dl) * Mrows + row0;
  const float4* dp = (const float4*)(DTg + base);
  const float4* fp = (const float4*)(Fg  + base);

#pragma unroll 4
  for (int tq = 0; tq < 16; ++tq) {
    const float4 dv = dp[tq];
    const float4 fv = fp[tq];
    float4 y4;
#define SCAN_STEP(DT, FF, YS)                                                 \
    {                                                                         \
      h = h * __expf((DT) * Af) + Bf * (FF);                                  \
      float y = h * Cf;                                                       \
      y += __int_as_float(__builtin_amdgcn_update_dpp(                        \
               0, __float_as_int(y), 0x111, 0xf, 0xf, true));                 \
      y += __int_as_float(__builtin_amdgcn_update_dpp(                        \
               0, __float_as_int(y), 0x112, 0xf, 0xf, true));                 \
      y += __int_as_float(__builtin_amdgcn_update_dpp(                        \
               0, __float_as_int(y), 0x114, 0xf, 0xf, true));                 \
      y += __int_as_float(__builtin_amdgcn_update_dpp(                        \
               0, __float_as_int(y), 0x118, 0xf, 0xf, true));                 \
      YS = y;                                                                 \
    }
    SCAN_STEP(dv.x, fv.x, y4.x);
    SCAN_STEP(dv.y, fv.y, y4.y);
    SCAN_STEP(dv.z, fv.z, y4.z);
    SCAN_STEP(dv.w, fv.w, y4.w);
#undef SCAN_STEP
    if (n == 15) *(float4*)&ys[dl][4 * tq] = y4;
  }
  __syncthreads();

  // gate: ZG[t][d] *= y[t][d], one ushort4 RMW per thread (64t x 4 quads)
  {
    const int tl = tid >> 2, p4 = (tid & 3) * 4;
    const size_t gi = (size_t)(row0 + tl) * DI + d0 + p4;
    ushort4 zv = *(const ushort4*)&ZG[gi];
    ushort4 ov;
    ov.x = __builtin_bit_cast(unsigned short, f2b(ys[p4 + 0][tl] * bfbits2f(zv.x)));
    ov.y = __builtin_bit_cast(unsigned short, f2b(ys[p4 + 1][tl] * bfbits2f(zv.y)));
    ov.z = __builtin_bit_cast(unsigned short, f2b(ys[p4 + 2][tl] * bfbits2f(zv.z)));
    ov.w = __builtin_bit_cast(unsigned short, f2b(ys[p4 + 3][tl] * bfbits2f(zv.w)));
    *(ushort4*)&ZG[gi] = ov;
  }
}

// --------------------------------------------------------------------------
// k2: out = G @ Wo^T + bo + meanDv*x  (bf16 MFMA, fp32 acc, pure store).
// --------------------------------------------------------------------------
__global__ __launch_bounds__(256)
void k2(const bf16* __restrict__ G, const bf16* __restrict__ W,
        const float* __restrict__ x, const float* __restrict__ bo,
        const float* __restrict__ meanp, float* __restrict__ out)
{
  __shared__ bf16 Al[128 * 32];
  __shared__ bf16 Bl[128 * 32];
  const int tid  = threadIdx.x;
  const int bm   = blockIdx.y * 128;
  const int bn   = blockIdx.x * 128;
  const int lane = tid & 63, wid = tid >> 6;
  const int wr = wid >> 1, wc = wid & 1;
  const int fr = lane & 15;
  const int kg = (lane >> 4) * 8;
  const int ldr = tid >> 2, ldc = (tid & 3) * 8;
  constexpr int K = DI;

  const bf16* ga = G + (size_t)(bm + ldr) * K + ldc;
  const bf16* gb = W + (size_t)(bn + ldr) * K + ldc;
  const float mv = *meanp;

  f32x4 acc[4][4];
#pragma unroll
  for (int i = 0; i < 4; ++i)
#pragma unroll
    for (int j = 0; j < 4; ++j) acc[i][j] = (f32x4){0.f, 0.f, 0.f, 0.f};

  for (int k0 = 0; k0 < K; k0 += 32) {
    GLOAD_LDS16(ga + k0,          &Al[tid * 8]);
    GLOAD_LDS16(ga + k0 + 64 * K, &Al[2048 + tid * 8]);
    GLOAD_LDS16(gb + k0,          &Bl[tid * 8]);
    GLOAD_LDS16(gb + k0 + 64 * K, &Bl[2048 + tid * 8]);
    asm volatile("s_waitcnt vmcnt(0)" ::: "memory");
    __syncthreads();
    bf16x8 af[4], bfr[4];
#pragma unroll
    for (int i = 0; i < 4; ++i)
      af[i]  = *(const bf16x8*)&Al[(wr * 64 + i * 16 + fr) * 32 + kg];
#pragma unroll
    for (int j = 0; j < 4; ++j)
      bfr[j] = *(const bf16x8*)&Bl[(wc * 64 + j * 16 + fr) * 32 + kg];
#pragma unroll
    for (int i = 0; i < 4; ++i)
#pragma unroll
      for (int j = 0; j < 4; ++j)
        acc[i][j] = __builtin_amdgcn_mfma_f32_16x16x32_bf16(
            af[i], bfr[j], acc[i][j], 0, 0, 0);
    __syncthreads();
  }

  const int r0 = (lane >> 4) * 4;
#pragma unroll
  for (int j = 0; j < 4; ++j) {
    const int col = bn + wc * 64 + j * 16 + fr;
    const float bv = bo[col];
#pragma unroll
    for (int i = 0; i < 4; ++i) {
      const int rowb = bm + wr * 64 + i * 16 + r0;
#pragma unroll
      for (int r = 0; r < 4; ++r) {
        const size_t oi = (size_t)(rowb + r) * DM + col;
        out[oi] = acc[i][j][r] + bv + mv * x[oi];
      }
    }
  }
}

// --------------------------------------------------------------------------
extern "C" void kernel_launch(void* const* d_in, const int* in_sizes, int n_in,
                              void* d_out, int out_size, void* d_ws, size_t ws_size,
                              hipStream_t stream)
{
  const float* x    = (const float*)d_in[0];
  const float* Wi   = (const float*)d_in[1];
  const float* bi   = (const float*)d_in[2];
  const float* cw   = (const float*)d_in[3];
  const float* cb   = (const float*)d_in[4];
  const float* Wdt  = (const float*)d_in[5];
  const float* bdt  = (const float*)d_in[6];
  const float* Alog = (const float*)d_in[7];
  const float* Bm   = (const float*)d_in[8];
  const float* Cm   = (const float*)d_in[9];
  const float* Dv   = (const float*)d_in[10];
  const float* Wo   = (const float*)d_in[11];
  const float* bo   = (const float*)d_in[12];
  float* out = (float*)d_out;

  char* ws = (char*)d_ws;
  float* MEANP = (float*)(ws);
  bf16*  WOB   = (bf16*)(ws + 256);
  bf16*  XIN   = (bf16*)(ws + 4194560);
  bf16*  ZG    = (bf16*)(ws + 37748992);
  float* APROD = (float*)(ws + 71303424);
  float* HEND  = (float*)(ws + 88080640);
  float* HINIT = (float*)(ws + 104857856);
  bf16*  WDTB  = (bf16*)(ws + 121635072);
  float* DTg   = (float*)(ws + 121766144);
  bf16*  XB    = (bf16*)(ws + 121766144);   // alias in DTg, dead after k1
  bf16*  WIB   = (bf16*)(ws + 138543360);   // alias in DTg, dead after k1
  float* Fg    = (float*)(ws + 188875008);
  // total ws use: 255,983,872 B

  kmean<<<1, 256, 0, stream>>>(Dv, MEANP);
  kcvt<<<Mrows * DM / 8 / 256, 256, 0, stream>>>(x,  XB,  Mrows * DM / 8);
  kcvt<<<2 * DI * DM / 8 / 256, 256, 0, stream>>>(Wi, WIB, 2 * DI * DM / 8);
  kcvt<<<DM * DI / 8 / 256, 256, 0, stream>>>(Wo, WOB, DM * DI / 8);
  kcvt<<<DI * DTR / 8 / 256, 256, 0, stream>>>(Wdt, WDTB, DI * DTR / 8);

  k1<<<dim3(2 * DI / 128, Mrows / 128), 256, 0, stream>>>(XB, WIB, bi, XIN, ZG);

  kscanA<<<dim3(DI / 16, Mrows / 64), 256, 0, stream>>>(
      XIN, WDTB, cw, cb, bdt, Alog, Bm, APROD, HEND, DTg, Fg);
  kscanH<<<dim3(Bdim * DI * DS / 256), 256, 0, stream>>>(APROD, HEND, HINIT);
  kscanB<<<dim3(DI / 16, Mrows / 64), 256, 0, stream>>>(
      DTg, Fg, ZG, Alog, Bm, Cm, HINIT);

  k2<<<dim3(DM / 128, Mrows / 128), 256, 0, stream>>>(ZG, WOB, x, bo, MEANP, out);
}

// Round 6
// 427.045 us; speedup vs baseline: 1.5786x; 1.1257x over previous
//
#include <hip/hip_runtime.h>
#include <hip/hip_bf16.h>
#include <math.h>
#include <stdint.h>

// SimpleSSMLayer on gfx950 — Round 15: lane-owns-(d,chunk) consumer scan.
// R14 counters: kscanB 134.6 us, VALUBusy 87%, VGPR=16 — VALU-issue-bound on
// structural redundancy: per (d,n,t) slot ~8 lane-ops incl. a 4-step DPP tree,
// ys LDS round-trip + barrier + separate gate pass. This round:
//   * kscanB: one thread owns (d, chunk) with h[16]/A2[16]/Bc[16]/Cc[16] in
//     registers. Per step: one coalesced float2 load (packed dt,f) + 16x
//     {mul, v_exp, fma} + 16 fma into y + fused gate RMW. No DPP, no LDS,
//     no barriers. 1024 blocks, __launch_bounds__(256,4) caps VGPR at 128
//     (4 waves/SIMD; ILP-16 per step covers latency).
//   * kscanA: writes packed DFg[row][d] float2 (coalesced 128B groups) in a
//     separate write pass; suffix loop + APROD use exp2 with log2e folded
//     into Af (drops one mul per exp slot).
//   * exp2 via __builtin_amdgcn_exp2f in both.
// GEMMs k1/k2 (MFMA 128x128, verified), kcvt, kscanH unchanged.
// ws layout (bytes):
//   [0)          meanDv                 pad 256
//   [256)        WOB  : 1024x2048 bf16  =  4,194,304
//   [4194560)    XIN  : 8192x2048 bf16  = 33,554,432
//   [37748992)   ZG   : 8192x2048 bf16  = 33,554,432
//   [71303424)   APROD: B*P*DI*DS f32   = 16,777,216
//   [88080640)   HEND :                 = 16,777,216
//   [104857856)  HINIT:                 = 16,777,216
//   [121635072)  WDTB : 2048x32 bf16    =     131,072
//   [121766144)  DFg  : Mrows*DI float2 = 134,217,728
//     XB  alias @121766144 (16,777,216)  dead after k1
//     WIB alias @138543360 ( 8,388,608)  dead after k1
//   total 255,983,872 B

using bf16 = __hip_bfloat16;
typedef __attribute__((ext_vector_type(8))) __bf16 bf16x8;
typedef __attribute__((ext_vector_type(4))) float f32x4;

static constexpr int Bdim = 4;
static constexpr int Tdim = 2048;
static constexpr int DM   = 1024;
static constexpr int DI   = 2048;
static constexpr int DS   = 16;
static constexpr int DC   = 4;
static constexpr int DTR  = 32;
static constexpr int Mrows = Bdim * Tdim;   // 8192
static constexpr int P    = 32;             // scan chunks per batch
static constexpr int TC2  = Tdim / P;       // 64 steps per chunk
static constexpr float LOG2E = 1.44269504f;

__device__ __forceinline__ float b2f(bf16 v) { return __bfloat162float(v); }
__device__ __forceinline__ bf16  f2b(float v) { return __float2bfloat16(v); }
__device__ __forceinline__ float silu_f(float v) { return v / (1.0f + __expf(-v)); }
__device__ __forceinline__ float softplus_f(float v) {
  return (v > 15.0f) ? v : __logf(1.0f + __expf(v));
}
__device__ __forceinline__ float bfbits2f(unsigned short u) {
  return __uint_as_float((unsigned)u << 16);
}
__device__ __forceinline__ float exp2_f(float v) {
  return __builtin_amdgcn_exp2f(v);
}

#define GLOAD_LDS16(gp, lp)                                                  \
  __builtin_amdgcn_global_load_lds(                                          \
      (const __attribute__((address_space(1))) uint32_t*)(gp),               \
      (__attribute__((address_space(3))) uint32_t*)(lp), 16, 0, 0)

// --------------------------------------------------------------------------
__global__ __launch_bounds__(256)
void kmean(const float* __restrict__ Dv, float* __restrict__ meanp) {
  __shared__ float red[256];
  float s = 0.0f;
  for (int i = threadIdx.x; i < DI; i += 256) s += Dv[i];
  red[threadIdx.x] = s;
  __syncthreads();
  for (int o = 128; o > 0; o >>= 1) {
    if (threadIdx.x < o) red[threadIdx.x] += red[threadIdx.x + o];
    __syncthreads();
  }
  if (threadIdx.x == 0) *meanp = red[0] / (float)DI;
}

// fp32 -> bf16 bulk convert, 8 elems/thread
__device__ __forceinline__ unsigned pack2(float x, float y) {
  return (unsigned)__builtin_bit_cast(unsigned short, f2b(x)) |
         ((unsigned)__builtin_bit_cast(unsigned short, f2b(y)) << 16);
}
__global__ __launch_bounds__(256)
void kcvt(const float* __restrict__ src, bf16* __restrict__ dst, int n8) {
  const int i = blockIdx.x * 256 + threadIdx.x;
  if (i >= n8) return;
  const float4 a = reinterpret_cast<const float4*>(src)[2 * i];
  const float4 b = reinterpret_cast<const float4*>(src)[2 * i + 1];
  uint4 v;
  v.x = pack2(a.x, a.y); v.y = pack2(a.z, a.w);
  v.z = pack2(b.x, b.y); v.w = pack2(b.z, b.w);
  reinterpret_cast<uint4*>(dst)[i] = v;
}

// --------------------------------------------------------------------------
// k1: xz = x @ Wi^T + bi  (bf16 MFMA, fp32 acc). Grid (32,64).
// --------------------------------------------------------------------------
__global__ __launch_bounds__(256)
void k1(const bf16* __restrict__ A, const bf16* __restrict__ W,
        const float* __restrict__ bi,
        bf16* __restrict__ XIN, bf16* __restrict__ ZG)
{
  __shared__ bf16 Al[128 * 32];
  __shared__ bf16 Bl[128 * 32];
  const int tid  = threadIdx.x;
  const int bm   = blockIdx.y * 128;
  const int bn   = blockIdx.x * 128;
  const int lane = tid & 63, wid = tid >> 6;
  const int wr = wid >> 1, wc = wid & 1;
  const int fr = lane & 15;
  const int kg = (lane >> 4) * 8;
  const int ldr = tid >> 2, ldc = (tid & 3) * 8;
  constexpr int K = DM;

  const bf16* ga = A + (size_t)(bm + ldr) * K + ldc;
  const bf16* gb = W + (size_t)(bn + ldr) * K + ldc;

  f32x4 acc[4][4];
#pragma unroll
  for (int i = 0; i < 4; ++i)
#pragma unroll
    for (int j = 0; j < 4; ++j) acc[i][j] = (f32x4){0.f, 0.f, 0.f, 0.f};

  for (int k0 = 0; k0 < K; k0 += 32) {
    GLOAD_LDS16(ga + k0,          &Al[tid * 8]);
    GLOAD_LDS16(ga + k0 + 64 * K, &Al[2048 + tid * 8]);
    GLOAD_LDS16(gb + k0,          &Bl[tid * 8]);
    GLOAD_LDS16(gb + k0 + 64 * K, &Bl[2048 + tid * 8]);
    asm volatile("s_waitcnt vmcnt(0)" ::: "memory");
    __syncthreads();
    bf16x8 af[4], bfr[4];
#pragma unroll
    for (int i = 0; i < 4; ++i)
      af[i]  = *(const bf16x8*)&Al[(wr * 64 + i * 16 + fr) * 32 + kg];
#pragma unroll
    for (int j = 0; j < 4; ++j)
      bfr[j] = *(const bf16x8*)&Bl[(wc * 64 + j * 16 + fr) * 32 + kg];
#pragma unroll
    for (int i = 0; i < 4; ++i)
#pragma unroll
      for (int j = 0; j < 4; ++j)
        acc[i][j] = __builtin_amdgcn_mfma_f32_16x16x32_bf16(
            af[i], bfr[j], acc[i][j], 0, 0, 0);
    __syncthreads();
  }

  const int r0 = (lane >> 4) * 4;
#pragma unroll
  for (int j = 0; j < 4; ++j) {
    const int col = bn + wc * 64 + j * 16 + fr;
    const float bv = bi[col];
    const bool isx = (col < DI);           // wave-uniform (64-aligned split)
#pragma unroll
    for (int i = 0; i < 4; ++i) {
      const int rowb = bm + wr * 64 + i * 16 + r0;
#pragma unroll
      for (int r = 0; r < 4; ++r) {
        const float v = acc[i][j][r] + bv;
        if (isx) XIN[(size_t)(rowb + r) * DI + col]        = f2b(v);
        else     ZG [(size_t)(rowb + r) * DI + (col - DI)] = f2b(silu_f(v));
      }
    }
  }
}

// --------------------------------------------------------------------------
// kscanA: producer. Per 64-t chunk: conv+dt (MFMA) -> packed DFg[row][d]
// (float2{dt, f}) + chunk summaries APROD/HEND (suffix-sum, no serial exp
// chain, exp2 with folded log2e). Grid (DI/16, Mrows/64) = (128, 128).
// --------------------------------------------------------------------------
__global__ __launch_bounds__(256)
void kscanA(const bf16* __restrict__ XIN, const bf16* __restrict__ WDTB,
            const float* __restrict__ cw, const float* __restrict__ cb,
            const float* __restrict__ bdt,
            const float* __restrict__ A_log, const float* __restrict__ Bm,
            float* __restrict__ APROD, float* __restrict__ HEND,
            float2* __restrict__ DFg)
{
  __shared__ float xc[67][20];    // [t-3..t+63][d], 20-pad for float4 writes
  __shared__ float dts[16][68];   // [d][t]
  __shared__ float fs [16][68];   // [d][t], f = dt*u

  const int tid  = threadIdx.x;
  const int lane = tid & 63;
  const int wid  = tid >> 6;
  const int n  = tid & 15;
  const int dl = tid >> 4;
  const int d0 = blockIdx.x * 16;
  const int d  = d0 + dl;
  const int row0 = blockIdx.y * 64;          // global row (chunk start)
  const int b  = row0 >> 11;                 // row0 / Tdim
  const size_t rbase = (size_t)b * Tdim;
  const int t0 = row0 - (int)rbase;          // batch-local chunk start

  const int fr = lane & 15;
  const int kg = (lane >> 4) * 8;
  const float bdtf = bdt[d0 + fr];
  const bf16x8 wfrag = *(const bf16x8*)&WDTB[(size_t)(d0 + fr) * DTR + kg];

  const float Af2 = -__expf(A_log[(size_t)d * DS + n]) * LOG2E;  // log2e folded
  const float Bf  = Bm[(size_t)d * DS + n];
  const float w0 = cw[d * DC + 0], w1 = cw[d * DC + 1];
  const float w2 = cw[d * DC + 2], w3 = cw[d * DC + 3];
  const float c0 = cb[d];

  // stage conv window, vectorized: 67 rows x 16 d = 268 ushort4 units
  for (int e = tid; e < 67 * 4; e += 256) {
    const int i = e >> 2, p4 = (e & 3) * 4;
    const int rr = t0 + i - 3;
    float4 v;
    if (rr < 0) {
      v = make_float4(0.f, 0.f, 0.f, 0.f);
    } else {
      const ushort4 u =
          *(const ushort4*)&XIN[(rbase + rr) * DI + d0 + p4];
      v = make_float4(bfbits2f(u.x), bfbits2f(u.y), bfbits2f(u.z), bfbits2f(u.w));
    }
    *(float4*)&xc[i][p4] = v;
  }
  {                                          // dt = x[:, :32] @ Wdt^T via MFMA
    const bf16x8 xfrag =
        *(const bf16x8*)&XIN[(rbase + t0 + wid * 16 + fr) * DI + kg];
    f32x4 a = (f32x4){0.f, 0.f, 0.f, 0.f};
    a = __builtin_amdgcn_mfma_f32_16x16x32_bf16(xfrag, wfrag, a, 0, 0, 0);
    float4 dq;
    dq.x = softplus_f(a[0] + bdtf);
    dq.y = softplus_f(a[1] + bdtf);
    dq.z = softplus_f(a[2] + bdtf);
    dq.w = softplus_f(a[3] + bdtf);
    *(float4*)&dts[fr][wid * 16 + (lane >> 4) * 4] = dq;
  }
  __syncthreads();

  // conv + silu -> u; f = dt*u
#pragma unroll
  for (int q = 0; q < 4; ++q) {
    const int tl = n + 16 * q;
    const float cv = c0 + w0 * xc[tl][dl] + w1 * xc[tl + 1][dl]
                        + w2 * xc[tl + 2][dl] + w3 * xc[tl + 3][dl];
    const float uv  = silu_f(cv);
    fs[dl][tl] = dts[dl][tl] * uv;
  }
  __syncthreads();

  // coalesced packed write: DFg[row0+tl][d0+dd] = {dt, f}  (128B per 16-thr)
  for (int e = tid; e < 64 * 16; e += 256) {
    const int tl = e >> 4, dd = e & 15;
    DFg[(size_t)(row0 + tl) * DI + d0 + dd] =
        make_float2(dts[dd][tl], fs[dd][tl]);
  }

  // backward suffix-sum over the 64 steps (no dependent exp chain)
  float acc = 0.0f;
  float R   = 0.0f;
#pragma unroll 4
  for (int sq = 15; sq >= 0; --sq) {
    const float4 dv = *(const float4*)&dts[dl][4 * sq];
    const float4 fv = *(const float4*)&fs [dl][4 * sq];
#define ASTEP(DT, FF)                                                         \
    {                                                                         \
      acc += exp2_f(R * Af2) * (Bf * (FF));                                   \
      R += (DT);                                                              \
    }
    ASTEP(dv.w, fv.w); ASTEP(dv.z, fv.z); ASTEP(dv.y, fv.y); ASTEP(dv.x, fv.x);
#undef ASTEP
  }

  const size_t si = (size_t)blockIdx.y * DI * DS + (size_t)d * DS + n;
  APROD[si] = exp2_f(R * Af2);
  HEND [si] = acc;
}

// --------------------------------------------------------------------------
// kscanH: sequential combine over P=32 chunks -> per-chunk initial states.
// --------------------------------------------------------------------------
__global__ __launch_bounds__(256)
void kscanH(const float* __restrict__ APROD, const float* __restrict__ HEND,
            float* __restrict__ HINIT)
{
  const int idx = blockIdx.x * 256 + threadIdx.x;   // b*DI*DS + dn
  const int b  = idx / (DI * DS);
  const int dn = idx % (DI * DS);
  float H = 0.0f;
#pragma unroll
  for (int c = 0; c < P; ++c) {
    const size_t si = (size_t)(b * P + c) * DI * DS + dn;
    HINIT[si] = H;
    H = APROD[si] * H + HEND[si];
  }
}

// --------------------------------------------------------------------------
// kscanB: lane-owns-(d, chunk). h[16]/A2[16]/Bc[16]/Cc[16] in registers;
// per step one coalesced float2 load + 16x{mul,exp2,fma} + 16 fma into y
// + fused gate RMW. No LDS, no barriers, no DPP.
// Grid 1024 blocks x 256 thr: blockIdx>>3 = chunk (0..127),
// (blockIdx&7)*256+tid = d.
// --------------------------------------------------------------------------
__global__ __launch_bounds__(256, 4)
void kscanB(const float2* __restrict__ DFg, bf16* __restrict__ ZG,
            const float* __restrict__ A_log, const float* __restrict__ Bm,
            const float* __restrict__ Cm, const float* __restrict__ HINIT)
{
  const int tid  = threadIdx.x;
  const int cg   = blockIdx.x >> 3;                    // global chunk
  const int d    = ((blockIdx.x & 7) << 8) + tid;
  const int row0 = cg * 64;

  float A2[DS], Bc[DS], Cc[DS], h[DS];
#pragma unroll
  for (int nn = 0; nn < DS; ++nn) {
    A2[nn] = -__expf(A_log[(size_t)d * DS + nn]) * LOG2E;
    Bc[nn] = Bm[(size_t)d * DS + nn];
    Cc[nn] = Cm[(size_t)d * DS + nn];
    h [nn] = HINIT[(size_t)cg * DI * DS + (size_t)d * DS + nn];
  }

  const float2* dfp = DFg + (size_t)row0 * DI + d;
  bf16* zp = ZG + (size_t)row0 * DI + d;

#pragma unroll 4
  for (int t = 0; t < TC2; ++t) {
    const float2 df = dfp[(size_t)t * DI];
    float y = 0.0f;
#pragma unroll
    for (int nn = 0; nn < DS; ++nn) {
      const float e = exp2_f(df.x * A2[nn]);
      h[nn] = h[nn] * e + Bc[nn] * df.y;
      y += h[nn] * Cc[nn];
    }
    bf16* zt = zp + (size_t)t * DI;
    *zt = f2b(y * b2f(*zt));
  }
}

// --------------------------------------------------------------------------
// k2: out = G @ Wo^T + bo + meanDv*x  (bf16 MFMA, fp32 acc, pure store).
// --------------------------------------------------------------------------
__global__ __launch_bounds__(256)
void k2(const bf16* __restrict__ G, const bf16* __restrict__ W,
        const float* __restrict__ x, const float* __restrict__ bo,
        const float* __restrict__ meanp, float* __restrict__ out)
{
  __shared__ bf16 Al[128 * 32];
  __shared__ bf16 Bl[128 * 32];
  const int tid  = threadIdx.x;
  const int bm   = blockIdx.y * 128;
  const int bn   = blockIdx.x * 128;
  const int lane = tid & 63, wid = tid >> 6;
  const int wr = wid >> 1, wc = wid & 1;
  const int fr = lane & 15;
  const int kg = (lane >> 4) * 8;
  const int ldr = tid >> 2, ldc = (tid & 3) * 8;
  constexpr int K = DI;

  const bf16* ga = G + (size_t)(bm + ldr) * K + ldc;
  const bf16* gb = W + (size_t)(bn + ldr) * K + ldc;
  const float mv = *meanp;

  f32x4 acc[4][4];
#pragma unroll
  for (int i = 0; i < 4; ++i)
#pragma unroll
    for (int j = 0; j < 4; ++j) acc[i][j] = (f32x4){0.f, 0.f, 0.f, 0.f};

  for (int k0 = 0; k0 < K; k0 += 32) {
    GLOAD_LDS16(ga + k0,          &Al[tid * 8]);
    GLOAD_LDS16(ga + k0 + 64 * K, &Al[2048 + tid * 8]);
    GLOAD_LDS16(gb + k0,          &Bl[tid * 8]);
    GLOAD_LDS16(gb + k0 + 64 * K, &Bl[2048 + tid * 8]);
    asm volatile("s_waitcnt vmcnt(0)" ::: "memory");
    __syncthreads();
    bf16x8 af[4], bfr[4];
#pragma unroll
    for (int i = 0; i < 4; ++i)
      af[i]  = *(const bf16x8*)&Al[(wr * 64 + i * 16 + fr) * 32 + kg];
#pragma unroll
    for (int j = 0; j < 4; ++j)
      bfr[j] = *(const bf16x8*)&Bl[(wc * 64 + j * 16 + fr) * 32 + kg];
#pragma unroll
    for (int i = 0; i < 4; ++i)
#pragma unroll
      for (int j = 0; j < 4; ++j)
        acc[i][j] = __builtin_amdgcn_mfma_f32_16x16x32_bf16(
            af[i], bfr[j], acc[i][j], 0, 0, 0);
    __syncthreads();
  }

  const int r0 = (lane >> 4) * 4;
#pragma unroll
  for (int j = 0; j < 4; ++j) {
    const int col = bn + wc * 64 + j * 16 + fr;
    const float bv = bo[col];
#pragma unroll
    for (int i = 0; i < 4; ++i) {
      const int rowb = bm + wr * 64 + i * 16 + r0;
#pragma unroll
      for (int r = 0; r < 4; ++r) {
        const size_t oi = (size_t)(rowb + r) * DM + col;
        out[oi] = acc[i][j][r] + bv + mv * x[oi];
      }
    }
  }
}

// --------------------------------------------------------------------------
extern "C" void kernel_launch(void* const* d_in, const int* in_sizes, int n_in,
                              void* d_out, int out_size, void* d_ws, size_t ws_size,
                              hipStream_t stream)
{
  const float* x    = (const float*)d_in[0];
  const float* Wi   = (const float*)d_in[1];
  const float* bi   = (const float*)d_in[2];
  const float* cw   = (const float*)d_in[3];
  const float* cb   = (const float*)d_in[4];
  const float* Wdt  = (const float*)d_in[5];
  const float* bdt  = (const float*)d_in[6];
  const float* Alog = (const float*)d_in[7];
  const float* Bm   = (const float*)d_in[8];
  const float* Cm   = (const float*)d_in[9];
  const float* Dv   = (const float*)d_in[10];
  const float* Wo   = (const float*)d_in[11];
  const float* bo   = (const float*)d_in[12];
  float* out = (float*)d_out;

  char* ws = (char*)d_ws;
  float*  MEANP = (float*)(ws);
  bf16*   WOB   = (bf16*)(ws + 256);
  bf16*   XIN   = (bf16*)(ws + 4194560);
  bf16*   ZG    = (bf16*)(ws + 37748992);
  float*  APROD = (float*)(ws + 71303424);
  float*  HEND  = (float*)(ws + 88080640);
  float*  HINIT = (float*)(ws + 104857856);
  bf16*   WDTB  = (bf16*)(ws + 121635072);
  float2* DFg   = (float2*)(ws + 121766144);
  bf16*   XB    = (bf16*)(ws + 121766144);   // alias in DFg, dead after k1
  bf16*   WIB   = (bf16*)(ws + 138543360);   // alias in DFg, dead after k1
  // total ws use: 255,983,872 B

  kmean<<<1, 256, 0, stream>>>(Dv, MEANP);
  kcvt<<<Mrows * DM / 8 / 256, 256, 0, stream>>>(x,  XB,  Mrows * DM / 8);
  kcvt<<<2 * DI * DM / 8 / 256, 256, 0, stream>>>(Wi, WIB, 2 * DI * DM / 8);
  kcvt<<<DM * DI / 8 / 256, 256, 0, stream>>>(Wo, WOB, DM * DI / 8);
  kcvt<<<DI * DTR / 8 / 256, 256, 0, stream>>>(Wdt, WDTB, DI * DTR / 8);

  k1<<<dim3(2 * DI / 128, Mrows / 128), 256, 0, stream>>>(XB, WIB, bi, XIN, ZG);

  kscanA<<<dim3(DI / 16, Mrows / 64), 256, 0, stream>>>(
      XIN, WDTB, cw, cb, bdt, Alog, Bm, APROD, HEND, DFg);
  kscanH<<<dim3(Bdim * DI * DS / 256), 256, 0, stream>>>(APROD, HEND, HINIT);
  kscanB<<<dim3(Mrows / 64 * 8), 256, 0, stream>>>(
      DFg, ZG, Alog, Bm, Cm, HINIT);

  k2<<<dim3(DM / 128, Mrows / 128), 256, 0, stream>>>(ZG, WOB, x, bo, MEANP, out);
}